// Round 3
// baseline (115.457 us; speedup 1.0000x reference)
//
#include <hip/hip_runtime.h>

// CrossProductLayer: out[b, f] = t(b, f) * w[f]
//   f in [0,128)    : x[b,f]^2
//   f in [128,256)  : x[b,f-128]
//   f in [256,8384) : x[b,i]*x[b,j]*0.5, (i,j) = triu_indices(128, k=1)[f-256]
// B=16384, F=8384. 549 MB fp32 output -> HBM-write-bound.
//
// R3: slab blocks (8 full rows per block -> contiguous 268 KB writes, x read
// exactly once), pair-index decode hoisted to a tiny setup kernel writing a
// u16 (i,j) table + prescaled w into d_ws. Singles handled branchlessly via a
// sentinel 1.0 column so the main loop is uniformly xr[i]*xr[j]*ws.
// fp-exact vs reference: *0.5 and *1.0 are exact scalings.

constexpr int BATCH   = 16384;
constexpr int NIN     = 128;
constexpr int NFEAT   = NIN + NIN + (NIN * (NIN - 1)) / 2;  // 8384
constexpr int TPB     = 256;
constexpr int ROWS    = 8;                                   // rows per block
constexpr int RSTRIDE = 132;  // floats; 528 B rows keep float4 stage 16B-aligned
constexpr int KITERS  = (NFEAT + TPB - 1) / TPB;             // 33

__device__ __forceinline__ int pair_off(int i) {
    return i * (NIN - 1) - (i * (i - 1)) / 2;
}

__device__ __forceinline__ void decode_f(int f, float w, int& i, int& j, float& ws) {
    if (f < NIN)          { i = f;       j = f;   ws = w; }
    else if (f < 2 * NIN) { i = f - NIN; j = NIN; ws = w; }  // col 128 holds 1.0
    else {
        const int p = f - 2 * NIN;
        float s = sqrtf((float)(65025 - 8 * p));
        int  ii = (int)((255.0f - s) * 0.5f);
        ii = min(max(ii, 0), NIN - 2);
        while (pair_off(ii + 1) <= p) ++ii;   // exact integer fix-up
        while (pair_off(ii)     >  p) --ii;
        i = ii; j = ii + 1 + (p - pair_off(ii));
        ws = w * 0.5f;                         // exact scaling
    }
}

__global__ void setup_kernel(const float* __restrict__ w,
                             float* __restrict__ wsb,
                             unsigned short* __restrict__ tbl) {
    const int f = blockIdx.x * TPB + threadIdx.x;
    if (f >= NFEAT) return;
    int i, j; float ws;
    decode_f(f, w[f], i, j, ws);
    wsb[f] = ws;
    tbl[f] = (unsigned short)((i << 8) | j);
}

template <bool USE_TBL>
__global__ __launch_bounds__(TPB) void cpl_kernel(const float* __restrict__ x,
                                                  const float* __restrict__ w,
                                                  const float* __restrict__ wsb,
                                                  const unsigned short* __restrict__ tbl,
                                                  float* __restrict__ out) {
    __shared__ float xs[ROWS * RSTRIDE];
    const int tid = threadIdx.x;
    const int r0  = blockIdx.x * ROWS;

    // Stage this block's 8x128 x-tile (read exactly once across the grid).
    {
        const int r = tid >> 5, c = (tid & 31) * 4;
        float4 v = *reinterpret_cast<const float4*>(x + (size_t)(r0 + r) * NIN + c);
        *reinterpret_cast<float4*>(&xs[r * RSTRIDE + c]) = v;
    }
    if (tid < ROWS) xs[tid * RSTRIDE + NIN] = 1.0f;  // sentinel for singles
    __syncthreads();

    // Software-pipelined table prefetch.
    unsigned short e_nx = 0; float w_nx = 0.0f;
    if (USE_TBL) { e_nx = tbl[tid]; w_nx = wsb[tid]; }

    for (int k = 0; k < KITERS; ++k) {
        const int f = k * TPB + tid;
        int i, j; float ws;
        if (USE_TBL) {
            const unsigned short e = e_nx; ws = w_nx;
            const int fn = min(f + TPB, NFEAT - 1);
            e_nx = tbl[fn]; w_nx = wsb[fn];
            i = e >> 8; j = e & 255;
        } else {
            if (f < NFEAT) decode_f(f, w[f], i, j, ws);
            else           { i = 0; j = 0; ws = 0.0f; }
        }
        if (f < NFEAT) {  // only k==32, tid>=192 (one fully-idle wave)
            float* op = out + (size_t)r0 * NFEAT + f;
#pragma unroll
            for (int r = 0; r < ROWS; ++r) {
                const float* xr = &xs[r * RSTRIDE];
                op[(size_t)r * NFEAT] = xr[i] * xr[j] * ws;  // lane-stride-1 LDS reads
            }
        }
    }
}

extern "C" void kernel_launch(void* const* d_in, const int* in_sizes, int n_in,
                              void* d_out, int out_size, void* d_ws, size_t ws_size,
                              hipStream_t stream) {
    const float* x = (const float*)d_in[0];  // [16384, 128]
    const float* w = (const float*)d_in[1];  // [8384]
    float*     out = (float*)d_out;          // [16384, 8384]

    const size_t need = (size_t)NFEAT * sizeof(float) + (size_t)NFEAT * sizeof(unsigned short);
    float*          wsb = (float*)d_ws;
    unsigned short* tbl = (unsigned short*)((char*)d_ws + (size_t)NFEAT * sizeof(float));

    const dim3 grid(BATCH / ROWS);  // 2048 blocks, 8 rows each (contiguous slabs)

    if (ws_size >= need) {
        setup_kernel<<<(NFEAT + TPB - 1) / TPB, TPB, 0, stream>>>(w, wsb, tbl);
        cpl_kernel<true><<<grid, TPB, 0, stream>>>(x, w, wsb, tbl, out);
    } else {
        cpl_kernel<false><<<grid, TPB, 0, stream>>>(x, w, wsb, tbl, out);
    }
}

// Round 4
// 110.597 us; speedup vs baseline: 1.0439x; 1.0439x over previous
//
#include <hip/hip_runtime.h>

// CrossProductLayer: out[b, f] = t(b, f) * w[f]
//   f in [0,128)    : x[b,f]^2
//   f in [128,256)  : x[b,f-128]
//   f in [256,8384) : x[b,i]*x[b,j]*0.5, (i,j) = triu_indices(128, k=1)[f-256]
// B=16384, F=8384. 549 MB fp32 output -> HBM-write-bound.
//
// R4: R2's block structure (feature-window x 32 rows, decode once per block)
// + one QUAD of features per thread -> float4 stores (1 KB/wave-instr, 1/4
// the store/addr instructions). LDS rows are stored SWIZZLED
// (word c -> (c&3)*32 + (c>>2)) so the quad's stride-4 j-reads become
// lane-stride-1 = conflict-free (R1's 8-way conflict fixed structurally).
// Sentinel 1.0 at word 128 of each row makes the inner loop branch-free:
// out = xa * xb * ws for all three regions.
// fp-exact: *1.0 exact; (xi*xj)*(0.5*w) == ((xi*xj)*0.5)*w (validated R3).

constexpr int BATCH = 16384;
constexpr int NIN   = 128;
constexpr int NPAIR = NIN * (NIN - 1) / 2;   // 8128
constexpr int NFEAT = 2 * NIN + NPAIR;       // 8384
constexpr int NQUAD = NFEAT / 4;             // 2096 (exact)
constexpr int TPB   = 256;
constexpr int BROWS = 32;
constexpr int RS    = 132;                   // LDS row stride (words); word 128 = 1.0

__device__ __forceinline__ int swz(int c) { return (c & 3) * 32 + (c >> 2); }
__device__ __forceinline__ int pair_off(int i) { return i * (NIN - 1) - (i * (i - 1)) / 2; }

__global__ __launch_bounds__(TPB) void cpl_kernel(const float* __restrict__ x,
                                                  const float* __restrict__ w,
                                                  float* __restrict__ out) {
    __shared__ float xs[BROWS * RS];
    const int tid = threadIdx.x;
    const int r0  = blockIdx.y * BROWS;

    // Stage 32x128 tile into swizzled LDS layout.
    // swz(c4+q) = q*32 + (tid&31): per-q write is lane-stride-1 -> conflict-free.
#pragma unroll
    for (int p = 0; p < BROWS * 32 / TPB; ++p) {  // 4 passes, 8 rows each
        const int r  = p * (TPB / 32) + (tid >> 5);
        const int c4 = (tid & 31) * 4;
        float4 v = *reinterpret_cast<const float4*>(x + (size_t)(r0 + r) * NIN + c4);
        float* row = &xs[r * RS];
        row[0 * 32 + (tid & 31)] = v.x;
        row[1 * 32 + (tid & 31)] = v.y;
        row[2 * 32 + (tid & 31)] = v.z;
        row[3 * 32 + (tid & 31)] = v.w;
    }
    if (tid < BROWS) xs[tid * RS + 128] = 1.0f;  // sentinel for singles
    __syncthreads();

    const int qd = blockIdx.x * TPB + tid;
    if (qd >= NQUAD) return;
    const int f0 = qd * 4;

    // Per-thread setup (diverges only here; inner loop is uniform).
    const float4 w4 = *reinterpret_cast<const float4*>(w + f0);
    const float* wp = reinterpret_cast<const float*>(&w4);
    int   ia[4], ib[4];
    float ws[4];
    if (f0 < NIN) {                       // squares: x*x
#pragma unroll
        for (int q = 0; q < 4; ++q) { ia[q] = swz(f0 + q); ib[q] = ia[q]; ws[q] = wp[q]; }
    } else if (f0 < 2 * NIN) {            // singles: x*1.0
#pragma unroll
        for (int q = 0; q < 4; ++q) { ia[q] = swz(f0 - NIN + q); ib[q] = 128; ws[q] = wp[q]; }
    } else {                              // pairs: xi*xj*(0.5*w)
        const int p0 = f0 - 2 * NIN;
        float s = sqrtf((float)(65025 - 8 * p0));
        int   i = (int)((255.0f - s) * 0.5f);
        i = min(max(i, 0), NIN - 2);
        while (pair_off(i + 1) <= p0) ++i;   // exact integer fix-up
        while (pair_off(i)     >  p0) --i;
        int j = i + 1 + (p0 - pair_off(i));
#pragma unroll
        for (int q = 0; q < 4; ++q) {
            ia[q] = swz(i); ib[q] = swz(j); ws[q] = wp[q] * 0.5f;
            if (++j > NIN - 1) { ++i; j = i + 1; }   // walk to next feature
        }
    }

    float* op = out + (size_t)r0 * NFEAT + f0;
#pragma unroll 4
    for (int r = 0; r < BROWS; ++r) {
        const float* xr = &xs[r * RS];
        float4 v;
        v.x = xr[ia[0]] * xr[ib[0]] * ws[0];
        v.y = xr[ia[1]] * xr[ib[1]] * ws[1];
        v.z = xr[ia[2]] * xr[ib[2]] * ws[2];
        v.w = xr[ia[3]] * xr[ib[3]] * ws[3];
        *reinterpret_cast<float4*>(op) = v;
        op += NFEAT;
    }
}

extern "C" void kernel_launch(void* const* d_in, const int* in_sizes, int n_in,
                              void* d_out, int out_size, void* d_ws, size_t ws_size,
                              hipStream_t stream) {
    const float* x = (const float*)d_in[0];  // [16384, 128]
    const float* w = (const float*)d_in[1];  // [8384]
    float*     out = (float*)d_out;          // [16384, 8384]

    dim3 grid((NQUAD + TPB - 1) / TPB,  // 9
              BATCH / BROWS);           // 512
    cpl_kernel<<<grid, TPB, 0, stream>>>(x, w, out);
}